// Round 5
// baseline (536.889 us; speedup 1.0000x reference)
//
#include <hip/hip_runtime.h>

// Problem constants (fixed by the reference setup)
#define NN 100000          // N_NODES
#define NE 1600000         // N_EDGES
#define IND 128            // IN_DIM
#define FD 32              // OUT_DIM
#define NH 8               // HEADS
#define HF 256             // NH*FD
#define ETOT 1700000       // NE + NN self loops
#define NB 391             // ceil(NN/256) scan blocks

// bf16 helpers (RNE), bit-level to avoid header variance
static __device__ __forceinline__ unsigned short f2bf(float f) {
  union { float f; unsigned u; } v; v.f = f;
  unsigned r = v.u + 0x7FFF + ((v.u >> 16) & 1);
  return (unsigned short)(r >> 16);
}
static __device__ __forceinline__ float bf2f(unsigned short u) {
  union { unsigned u; float f; } v; v.u = ((unsigned)u) << 16;
  return v.f;
}

// ---------------------------------------------------------------------------
// K1: projection GEMM fused with attention logits (unchanged core from R4).
// h stored bf16; a_src/a_dst computed fp32-exact from the accumulators.
// ---------------------------------------------------------------------------
__global__ __launch_bounds__(256) void k_gemm(const float* __restrict__ X,
                                              const float* __restrict__ W,
                                              const float* __restrict__ att_src,
                                              const float* __restrict__ att_dst,
                                              unsigned short* __restrict__ HhB,
                                              float* __restrict__ AS,
                                              float* __restrict__ AD) {
  __shared__ __align__(16) float Xs[16 * 132];   // +4 pad breaks 128-stride
  __shared__ float redS[16 * 65];
  __shared__ float redD[16 * 65];
  const int n0 = blockIdx.x * 16;
  const int t = threadIdx.x;
#pragma unroll
  for (int j = 0; j < 8; ++j) {
    int idx = t + j * 256;
    int r = idx >> 7, c = idx & 127;
    Xs[r * 132 + c] = X[(n0 + r) * IND + c];
  }
  __syncthreads();

  const int cg = t >> 2;
  const int c0 = cg * 4;
  const int ng = t & 3;

  float4 acc[4];
#pragma unroll
  for (int i = 0; i < 4; ++i) acc[i] = make_float4(0.f, 0.f, 0.f, 0.f);

  for (int k0 = 0; k0 < IND; k0 += 4) {
    const float4 w0 = *(const float4*)(W + (k0 + 0) * HF + c0);
    const float4 w1 = *(const float4*)(W + (k0 + 1) * HF + c0);
    const float4 w2 = *(const float4*)(W + (k0 + 2) * HF + c0);
    const float4 w3 = *(const float4*)(W + (k0 + 3) * HF + c0);
#pragma unroll
    for (int i = 0; i < 4; ++i) {
      const float4 xv = *(const float4*)(Xs + (ng * 4 + i) * 132 + k0);
      acc[i].x += xv.x * w0.x + xv.y * w1.x + xv.z * w2.x + xv.w * w3.x;
      acc[i].y += xv.x * w0.y + xv.y * w1.y + xv.z * w2.y + xv.w * w3.y;
      acc[i].z += xv.x * w0.z + xv.y * w1.z + xv.z * w2.z + xv.w * w3.z;
      acc[i].w += xv.x * w0.w + xv.y * w1.w + xv.z * w2.w + xv.w * w3.w;
    }
  }

#pragma unroll
  for (int i = 0; i < 4; ++i) {
    ushort4 u;
    u.x = f2bf(acc[i].x); u.y = f2bf(acc[i].y);
    u.z = f2bf(acc[i].z); u.w = f2bf(acc[i].w);
    *(ushort4*)(HhB + (size_t)(n0 + ng * 4 + i) * HF + c0) = u;
  }

  const float4 vs = *(const float4*)(att_src + c0);
  const float4 vd = *(const float4*)(att_dst + c0);
#pragma unroll
  for (int i = 0; i < 4; ++i) {
    int r = ng * 4 + i;
    redS[r * 65 + cg] = acc[i].x * vs.x + acc[i].y * vs.y +
                        acc[i].z * vs.z + acc[i].w * vs.w;
    redD[r * 65 + cg] = acc[i].x * vd.x + acc[i].y * vd.y +
                        acc[i].z * vd.z + acc[i].w * vd.w;
  }
  __syncthreads();

  if (t < 128) {
    int r = t >> 3, hh = t & 7;
    float s = 0.f;
#pragma unroll
    for (int k = 0; k < 8; ++k) s += redS[r * 65 + hh * 8 + k];
    AS[(n0 + r) * NH + hh] = s;
  } else {
    int tt = t - 128;
    int r = tt >> 3, hh = tt & 7;
    float s = 0.f;
#pragma unroll
    for (int k = 0; k < 8; ++k) s += redD[r * 65 + hh * 8 + k];
    AD[(n0 + r) * NH + hh] = s;
  }
}

// ---------------------------------------------------------------------------
// CSR build: histogram -> 2-level exclusive scan -> scatter
// ---------------------------------------------------------------------------
__global__ __launch_bounds__(256) void k_hist(const int* __restrict__ ei,
                                              int* __restrict__ cnt) {
  int tid = blockIdx.x * 256 + threadIdx.x;
  if (tid >= ETOT) return;
  int d = (tid < NE) ? ei[NE + tid] : (tid - NE);
  atomicAdd(&cnt[d], 1);
}

__global__ __launch_bounds__(256) void k_scan1(const int* __restrict__ cnt,
                                               int* __restrict__ lpre,
                                               int* __restrict__ bsum) {
  __shared__ int sd[256];
  int t = threadIdx.x, i = blockIdx.x * 256 + t;
  int v = (i < NN) ? cnt[i] : 0;
  sd[t] = v; __syncthreads();
  for (int off = 1; off < 256; off <<= 1) {
    int x = (t >= off) ? sd[t - off] : 0;
    __syncthreads();
    sd[t] += x;
    __syncthreads();
  }
  if (i < NN) lpre[i] = sd[t] - v;        // block-local exclusive prefix
  if (t == 255) bsum[blockIdx.x] = sd[255];
}

__global__ __launch_bounds__(512) void k_scan2(const int* __restrict__ bsum,
                                               int* __restrict__ boff) {
  __shared__ int sd[512];
  int t = threadIdx.x;
  int v = (t < NB) ? bsum[t] : 0;
  sd[t] = v; __syncthreads();
  for (int off = 1; off < 512; off <<= 1) {
    int x = (t >= off) ? sd[t - off] : 0;
    __syncthreads();
    sd[t] += x;
    __syncthreads();
  }
  if (t < NB) boff[t] = sd[t] - v;        // exclusive block offsets
}

__global__ __launch_bounds__(256) void k_scan3(const int* __restrict__ lpre,
                                               const int* __restrict__ boff,
                                               int* __restrict__ rowptr,
                                               int* __restrict__ cursor) {
  int i = blockIdx.x * 256 + threadIdx.x;
  if (i < NN) {
    int v = boff[blockIdx.x] + lpre[i];
    rowptr[i] = v;
    cursor[i] = v;
  }
  if (i == 0) rowptr[NN] = ETOT;          // total is a compile-time constant
}

__global__ __launch_bounds__(256) void k_scatter(const int* __restrict__ ei,
                                                 int* __restrict__ cursor,
                                                 int* __restrict__ csr) {
  int tid = blockIdx.x * 256 + threadIdx.x;
  if (tid >= ETOT) return;
  int s, d;
  if (tid < NE) { s = ei[tid]; d = ei[NE + tid]; } else { s = d = tid - NE; }
  int pos = atomicAdd(&cursor[d], 1);
  csr[pos] = s;
}

// ---------------------------------------------------------------------------
// K2: single-pass GAT aggregation. One wave per dst node (4 waves/block).
// Lane l: head hh=l>>3, feature chunk sub=l&7 (4 bf16 feats = 8 B/lane,
// wave reads the full 512-B src row in one instruction). Each lane
// accumulates den (its head) and 4 unnormalized sums in registers; exp is
// computed ONCE per (edge, head-octet); normalization happens after the
// loop, head-mean via xor-shuffles, direct coalesced store. No atomics,
// no second edge pass, no oac round-trip.
// ---------------------------------------------------------------------------
__global__ __launch_bounds__(256) void k_gat(const int* __restrict__ rowptr,
                                             const int* __restrict__ csr,
                                             const float* __restrict__ AS,
                                             const float* __restrict__ AD,
                                             const unsigned short* __restrict__ HhB,
                                             const float* __restrict__ bias,
                                             float* __restrict__ out) {
  const int d = blockIdx.x * 4 + (threadIdx.x >> 6);   // 25000*4 == NN exactly
  const int lane = threadIdx.x & 63;
  const int hh = lane >> 3, sub = lane & 7;
  const int start = rowptr[d], end = rowptr[d + 1];
  const float ad = AD[d * NH + hh];

  float den = 0.f, a0 = 0.f, a1 = 0.f, a2 = 0.f, a3 = 0.f;

  for (int base = start; base < end; base += 64) {
    int srcs = 0;
    if (base + lane < end) srcs = csr[base + lane];
    int m = end - base; if (m > 64) m = 64;
    int t = 0;
    for (; t + 1 < m; t += 2) {               // 2-way unroll for load ILP
      int s0 = __shfl(srcs, t, 64);
      int s1 = __shfl(srcs, t + 1, 64);
      float lg0 = AS[s0 * NH + hh] + ad;
      float lg1 = AS[s1 * NH + hh] + ad;
      ushort4 h0 = *(const ushort4*)(HhB + (size_t)s0 * HF + hh * 32 + sub * 4);
      ushort4 h1 = *(const ushort4*)(HhB + (size_t)s1 * HF + hh * 32 + sub * 4);
      lg0 = lg0 > 0.f ? lg0 : 0.2f * lg0;
      lg1 = lg1 > 0.f ? lg1 : 0.2f * lg1;
      float e0 = __expf(lg0), e1 = __expf(lg1);
      den += e0 + e1;
      a0 += e0 * bf2f(h0.x) + e1 * bf2f(h1.x);
      a1 += e0 * bf2f(h0.y) + e1 * bf2f(h1.y);
      a2 += e0 * bf2f(h0.z) + e1 * bf2f(h1.z);
      a3 += e0 * bf2f(h0.w) + e1 * bf2f(h1.w);
    }
    if (t < m) {
      int s0 = __shfl(srcs, t, 64);
      float lg0 = AS[s0 * NH + hh] + ad;
      ushort4 h0 = *(const ushort4*)(HhB + (size_t)s0 * HF + hh * 32 + sub * 4);
      lg0 = lg0 > 0.f ? lg0 : 0.2f * lg0;
      float e0 = __expf(lg0);
      den += e0;
      a0 += e0 * bf2f(h0.x); a1 += e0 * bf2f(h0.y);
      a2 += e0 * bf2f(h0.z); a3 += e0 * bf2f(h0.w);
    }
  }

  const float inv = 1.f / (den + 1e-16f);     // per-head normalization
  a0 *= inv; a1 *= inv; a2 *= inv; a3 *= inv;

#pragma unroll
  for (int off = 8; off < 64; off <<= 1) {    // sum over the 8 heads
    a0 += __shfl_xor(a0, off, 64);
    a1 += __shfl_xor(a1, off, 64);
    a2 += __shfl_xor(a2, off, 64);
    a3 += __shfl_xor(a3, off, 64);
  }

  if (lane < 8) {                             // lanes 0-7: features sub*4..+3
    float4 o;
    o.x = a0 * 0.125f + bias[sub * 4 + 0];
    o.y = a1 * 0.125f + bias[sub * 4 + 1];
    o.z = a2 * 0.125f + bias[sub * 4 + 2];
    o.w = a3 * 0.125f + bias[sub * 4 + 3];
    *(float4*)(out + (size_t)d * FD + sub * 4) = o;
  }
}

// ---------------------------------------------------------------------------
// Workspace layout:
//   HhB    bf16[N*256]            floats [0,          12,800,000)   51.2 MB
//   AS     float[N*8]                    [12,800,000, 13,600,000)    3.2 MB
//   AD     float[N*8]                    [13,600,000, 14,400,000)    3.2 MB
//   ints (base = ws + 14,400,000):
//     cnt    [0,       100,000)
//     lpre   [100,000, 200,000)
//     bsum   [200,000, 200,512)
//     boff   [200,512, 201,024)
//     rowptr [201,024, 301,025)
//     cursor [301,056, 401,056)
//     csr    [401,056, 2,101,056)                                    8.4 MB
// ---------------------------------------------------------------------------
extern "C" void kernel_launch(void* const* d_in, const int* in_sizes, int n_in,
                              void* d_out, int out_size, void* d_ws, size_t ws_size,
                              hipStream_t stream) {
  const float* X       = (const float*)d_in[0];
  const int*   ei      = (const int*)d_in[1];
  const float* W       = (const float*)d_in[2];
  const float* att_src = (const float*)d_in[3];
  const float* att_dst = (const float*)d_in[4];
  const float* bias    = (const float*)d_in[5];
  float* out = (float*)d_out;
  float* ws  = (float*)d_ws;

  unsigned short* HhB = (unsigned short*)ws;
  float* AS = ws + 12800000;
  float* AD = ws + 13600000;
  int* ib     = (int*)(ws + 14400000);
  int* cnt    = ib;
  int* lpre   = ib + 100000;
  int* bsum   = ib + 200000;
  int* boff   = ib + 200512;
  int* rowptr = ib + 201024;
  int* cursor = ib + 301056;
  int* csr    = ib + 401056;

  hipMemsetAsync(cnt, 0, (size_t)NN * sizeof(int), stream);

  k_gemm   <<<NN / 16, 256, 0, stream>>>(X, W, att_src, att_dst, HhB, AS, AD);
  k_hist   <<<(ETOT + 255) / 256, 256, 0, stream>>>(ei, cnt);
  k_scan1  <<<NB, 256, 0, stream>>>(cnt, lpre, bsum);
  k_scan2  <<<1, 512, 0, stream>>>(bsum, boff);
  k_scan3  <<<NB, 256, 0, stream>>>(lpre, boff, rowptr, cursor);
  k_scatter<<<(ETOT + 255) / 256, 256, 0, stream>>>(ei, cursor, csr);
  k_gat    <<<NN / 4, 256, 0, stream>>>(rowptr, csr, AS, AD, HhB, bias, out);
}

// Round 6
// 484.550 us; speedup vs baseline: 1.1080x; 1.1080x over previous
//
#include <hip/hip_runtime.h>

// Problem constants (fixed by the reference setup)
#define NN 100000          // N_NODES
#define NE 1600000         // N_EDGES
#define IND 128            // IN_DIM
#define FD 32              // OUT_DIM
#define NH 8               // HEADS
#define HF 256             // NH*FD
#define ETOT 1700000       // NE + NN self loops
#define NB 391             // ceil(NN/256) scan blocks

typedef __attribute__((ext_vector_type(8))) short bfrag;    // 8 bf16 (4 VGPRs)
typedef __attribute__((ext_vector_type(4))) float ffrag;    // 4 fp32 acc
typedef __attribute__((ext_vector_type(8))) unsigned short us8;

// bf16 helpers (RNE), bit-level to avoid header variance
static __device__ __forceinline__ unsigned short f2bf(float f) {
  union { float f; unsigned u; } v; v.f = f;
  unsigned r = v.u + 0x7FFF + ((v.u >> 16) & 1);
  return (unsigned short)(r >> 16);
}
static __device__ __forceinline__ float bf2f(unsigned short u) {
  union { unsigned u; float f; } v; v.u = ((unsigned)u) << 16;
  return v.f;
}

// ---------------------------------------------------------------------------
// K0: pack W (fp32 [128][256]) into MFMA B-operand order, bf16:
// Wp[((kt*256 + c)*32 + kk)] = bf16(W[(kt*32+kk)*256 + c]).
// A lane (col n=lane&15 within tile, quad=lane>>4) then loads its 8-element
// B fragment as ONE 16-byte read at ((kt*256+c)*32 + quad*8).
// ---------------------------------------------------------------------------
__global__ __launch_bounds__(256) void k_convW(const float* __restrict__ W,
                                               unsigned short* __restrict__ Wp) {
  int tid = blockIdx.x * 256 + threadIdx.x;   // 32768 threads
  int kk = tid & 31, c = (tid >> 5) & 255, kt = tid >> 13;
  Wp[tid] = f2bf(W[(kt * 32 + kk) * HF + c]);
}

// ---------------------------------------------------------------------------
// K1: MFMA bf16 projection GEMM fused with attention logits.
// 64 nodes x 256 cols per block; 4 waves, each wave: 16 nodes, full 256 cols
// via 16 col-tiles x 4 k-steps of v_mfma_f32_16x16x32_bf16.
// Fragment layouts (verified, guide §3):
//   A: lane holds A[m=lane&15][k=quad*8+j]   (16B contiguous in k)
//   B: lane holds B[k=quad*8+j][n=lane&15]   (16B contiguous via Wp packing)
//   C/D: col=lane&15, row=quad*4+reg
// Epilogue per head: 16x32 fp32 tile -> padded LDS scratch -> row-major
// readback: 16B coalesced bf16 h store + exact fp32 logit dot + shfl reduce.
// ---------------------------------------------------------------------------
__global__ __launch_bounds__(256) void k_gemm(const float* __restrict__ X,
                                              const unsigned short* __restrict__ Wp,
                                              const float* __restrict__ att_src,
                                              const float* __restrict__ att_dst,
                                              unsigned short* __restrict__ HhB,
                                              float* __restrict__ AS,
                                              float* __restrict__ AD) {
  __shared__ __align__(16) unsigned short Xs[64 * 136];  // stride 136: 2-way max
  __shared__ __align__(16) float Scr[4][16 * 36];        // per-wave transpose buf
  const int n0 = blockIdx.x * 64;
  const int t = threadIdx.x;

  // stage X tile fp32 -> bf16 LDS (64 lanes read 1KB contiguous per instr)
#pragma unroll
  for (int j = 0; j < 8; ++j) {
    int g = t + j * 256;            // float4-group id, 0..2047
    int r = g >> 5, c4 = g & 31;
    int gr = n0 + r; if (gr >= NN) gr = NN - 1;   // tail clamp (values unused)
    float4 x = *(const float4*)(X + (size_t)gr * IND + c4 * 4);
    ushort4 u;
    u.x = f2bf(x.x); u.y = f2bf(x.y); u.z = f2bf(x.z); u.w = f2bf(x.w);
    *(ushort4*)(Xs + r * 136 + c4 * 4) = u;
  }
  __syncthreads();

  const int w = t >> 6, lane = t & 63;
  const int quad = lane >> 4, m = lane & 15;
  const int rb = w * 16;

  bfrag afr[4];
#pragma unroll
  for (int kt = 0; kt < 4; ++kt)
    afr[kt] = *(const bfrag*)(Xs + (rb + m) * 136 + kt * 32 + quad * 8);

  ffrag acc[16];
#pragma unroll
  for (int ct = 0; ct < 16; ++ct) {
    ffrag c = {0.f, 0.f, 0.f, 0.f};
#pragma unroll
    for (int kt = 0; kt < 4; ++kt) {
      bfrag b = *(const bfrag*)(Wp + ((kt * 256 + ct * 16 + m) << 5) + quad * 8);
      c = __builtin_amdgcn_mfma_f32_16x16x32_bf16(afr[kt], b, c, 0, 0, 0);
    }
    acc[ct] = c;
  }

  // ---- epilogue: per head hp, transpose 16x32 tile through LDS ----
  const int row = lane >> 2, c3 = lane & 3;
  const int node_s = n0 + rb + row;
  float* S = &Scr[w][0];

#pragma unroll
  for (int hp = 0; hp < NH; ++hp) {
#pragma unroll
    for (int half = 0; half < 2; ++half) {
      ffrag c = acc[hp * 2 + half];
#pragma unroll
      for (int r = 0; r < 4; ++r)
        S[(quad * 4 + r) * 36 + half * 16 + m] = c[r];
    }
    __syncthreads();
    float4 v0 = *(const float4*)(S + row * 36 + c3 * 8);
    float4 v1 = *(const float4*)(S + row * 36 + c3 * 8 + 4);

    if (node_s < NN) {
      us8 u;
      u[0] = f2bf(v0.x); u[1] = f2bf(v0.y); u[2] = f2bf(v0.z); u[3] = f2bf(v0.w);
      u[4] = f2bf(v1.x); u[5] = f2bf(v1.y); u[6] = f2bf(v1.z); u[7] = f2bf(v1.w);
      *(us8*)(HhB + (size_t)node_s * HF + hp * 32 + c3 * 8) = u;   // 16B store
    }

    // fp32-exact logit partials over this lane's 8 cols of head hp
    float4 s0 = *(const float4*)(att_src + hp * 32 + c3 * 8);
    float4 s1 = *(const float4*)(att_src + hp * 32 + c3 * 8 + 4);
    float4 d0 = *(const float4*)(att_dst + hp * 32 + c3 * 8);
    float4 d1 = *(const float4*)(att_dst + hp * 32 + c3 * 8 + 4);
    float ss = v0.x * s0.x + v0.y * s0.y + v0.z * s0.z + v0.w * s0.w
             + v1.x * s1.x + v1.y * s1.y + v1.z * s1.z + v1.w * s1.w;
    float dd = v0.x * d0.x + v0.y * d0.y + v0.z * d0.z + v0.w * d0.w
             + v1.x * d1.x + v1.y * d1.y + v1.z * d1.z + v1.w * d1.w;
    ss += __shfl_xor(ss, 1, 64); ss += __shfl_xor(ss, 2, 64);
    dd += __shfl_xor(dd, 1, 64); dd += __shfl_xor(dd, 2, 64);
    if (c3 == 0 && node_s < NN) {
      AS[node_s * NH + hp] = ss;
      AD[node_s * NH + hp] = dd;
    }
    __syncthreads();   // WAR protection before next head reuses Scr
  }
}

// ---------------------------------------------------------------------------
// CSR build: histogram -> 2-level exclusive scan -> scatter (unchanged R5)
// ---------------------------------------------------------------------------
__global__ __launch_bounds__(256) void k_hist(const int* __restrict__ ei,
                                              int* __restrict__ cnt) {
  int tid = blockIdx.x * 256 + threadIdx.x;
  if (tid >= ETOT) return;
  int d = (tid < NE) ? ei[NE + tid] : (tid - NE);
  atomicAdd(&cnt[d], 1);
}

__global__ __launch_bounds__(256) void k_scan1(const int* __restrict__ cnt,
                                               int* __restrict__ lpre,
                                               int* __restrict__ bsum) {
  __shared__ int sd[256];
  int t = threadIdx.x, i = blockIdx.x * 256 + t;
  int v = (i < NN) ? cnt[i] : 0;
  sd[t] = v; __syncthreads();
  for (int off = 1; off < 256; off <<= 1) {
    int x = (t >= off) ? sd[t - off] : 0;
    __syncthreads();
    sd[t] += x;
    __syncthreads();
  }
  if (i < NN) lpre[i] = sd[t] - v;
  if (t == 255) bsum[blockIdx.x] = sd[255];
}

__global__ __launch_bounds__(512) void k_scan2(const int* __restrict__ bsum,
                                               int* __restrict__ boff) {
  __shared__ int sd[512];
  int t = threadIdx.x;
  int v = (t < NB) ? bsum[t] : 0;
  sd[t] = v; __syncthreads();
  for (int off = 1; off < 512; off <<= 1) {
    int x = (t >= off) ? sd[t - off] : 0;
    __syncthreads();
    sd[t] += x;
    __syncthreads();
  }
  if (t < NB) boff[t] = sd[t] - v;
}

__global__ __launch_bounds__(256) void k_scan3(const int* __restrict__ lpre,
                                               const int* __restrict__ boff,
                                               int* __restrict__ rowptr,
                                               int* __restrict__ cursor) {
  int i = blockIdx.x * 256 + threadIdx.x;
  if (i < NN) {
    int v = boff[blockIdx.x] + lpre[i];
    rowptr[i] = v;
    cursor[i] = v;
  }
  if (i == 0) rowptr[NN] = ETOT;
}

__global__ __launch_bounds__(256) void k_scatter(const int* __restrict__ ei,
                                                 int* __restrict__ cursor,
                                                 int* __restrict__ csr) {
  int tid = blockIdx.x * 256 + threadIdx.x;
  if (tid >= ETOT) return;
  int s, d;
  if (tid < NE) { s = ei[tid]; d = ei[NE + tid]; } else { s = d = tid - NE; }
  int pos = atomicAdd(&cursor[d], 1);
  csr[pos] = s;
}

// ---------------------------------------------------------------------------
// K2: single-pass GAT aggregation (unchanged R5). One wave per dst node.
// ---------------------------------------------------------------------------
__global__ __launch_bounds__(256) void k_gat(const int* __restrict__ rowptr,
                                             const int* __restrict__ csr,
                                             const float* __restrict__ AS,
                                             const float* __restrict__ AD,
                                             const unsigned short* __restrict__ HhB,
                                             const float* __restrict__ bias,
                                             float* __restrict__ out) {
  const int d = blockIdx.x * 4 + (threadIdx.x >> 6);   // 25000*4 == NN exactly
  const int lane = threadIdx.x & 63;
  const int hh = lane >> 3, sub = lane & 7;
  const int start = rowptr[d], end = rowptr[d + 1];
  const float ad = AD[d * NH + hh];

  float den = 0.f, a0 = 0.f, a1 = 0.f, a2 = 0.f, a3 = 0.f;

  for (int base = start; base < end; base += 64) {
    int srcs = 0;
    if (base + lane < end) srcs = csr[base + lane];
    int m = end - base; if (m > 64) m = 64;
    int t = 0;
    for (; t + 1 < m; t += 2) {               // 2-way unroll for load ILP
      int s0 = __shfl(srcs, t, 64);
      int s1 = __shfl(srcs, t + 1, 64);
      float lg0 = AS[s0 * NH + hh] + ad;
      float lg1 = AS[s1 * NH + hh] + ad;
      ushort4 h0 = *(const ushort4*)(HhB + (size_t)s0 * HF + hh * 32 + sub * 4);
      ushort4 h1 = *(const ushort4*)(HhB + (size_t)s1 * HF + hh * 32 + sub * 4);
      lg0 = lg0 > 0.f ? lg0 : 0.2f * lg0;
      lg1 = lg1 > 0.f ? lg1 : 0.2f * lg1;
      float e0 = __expf(lg0), e1 = __expf(lg1);
      den += e0 + e1;
      a0 += e0 * bf2f(h0.x) + e1 * bf2f(h1.x);
      a1 += e0 * bf2f(h0.y) + e1 * bf2f(h1.y);
      a2 += e0 * bf2f(h0.z) + e1 * bf2f(h1.z);
      a3 += e0 * bf2f(h0.w) + e1 * bf2f(h1.w);
    }
    if (t < m) {
      int s0 = __shfl(srcs, t, 64);
      float lg0 = AS[s0 * NH + hh] + ad;
      ushort4 h0 = *(const ushort4*)(HhB + (size_t)s0 * HF + hh * 32 + sub * 4);
      lg0 = lg0 > 0.f ? lg0 : 0.2f * lg0;
      float e0 = __expf(lg0);
      den += e0;
      a0 += e0 * bf2f(h0.x); a1 += e0 * bf2f(h0.y);
      a2 += e0 * bf2f(h0.z); a3 += e0 * bf2f(h0.w);
    }
  }

  const float inv = 1.f / (den + 1e-16f);
  a0 *= inv; a1 *= inv; a2 *= inv; a3 *= inv;

#pragma unroll
  for (int off = 8; off < 64; off <<= 1) {    // sum over the 8 heads
    a0 += __shfl_xor(a0, off, 64);
    a1 += __shfl_xor(a1, off, 64);
    a2 += __shfl_xor(a2, off, 64);
    a3 += __shfl_xor(a3, off, 64);
  }

  if (lane < 8) {
    float4 o;
    o.x = a0 * 0.125f + bias[sub * 4 + 0];
    o.y = a1 * 0.125f + bias[sub * 4 + 1];
    o.z = a2 * 0.125f + bias[sub * 4 + 2];
    o.w = a3 * 0.125f + bias[sub * 4 + 3];
    *(float4*)(out + (size_t)d * FD + sub * 4) = o;
  }
}

// ---------------------------------------------------------------------------
// Workspace layout:
//   HhB    bf16[N*256]            floats [0,          12,800,000)   51.2 MB
//   AS     float[N*8]                    [12,800,000, 13,600,000)    3.2 MB
//   AD     float[N*8]                    [13,600,000, 14,400,000)    3.2 MB
//   ints (base = ws + 14,400,000):
//     cnt    [0,       100,000)
//     lpre   [100,000, 200,000)
//     bsum   [200,000, 200,512)
//     boff   [200,512, 201,024)
//     rowptr [201,024, 301,025)
//     cursor [301,056, 401,056)
//     csr    [401,056, 2,101,056)
//     Wp     [2,101,056, 2,117,440)  (32768 bf16 = 16384 ints)
// ---------------------------------------------------------------------------
extern "C" void kernel_launch(void* const* d_in, const int* in_sizes, int n_in,
                              void* d_out, int out_size, void* d_ws, size_t ws_size,
                              hipStream_t stream) {
  const float* X       = (const float*)d_in[0];
  const int*   ei      = (const int*)d_in[1];
  const float* W       = (const float*)d_in[2];
  const float* att_src = (const float*)d_in[3];
  const float* att_dst = (const float*)d_in[4];
  const float* bias    = (const float*)d_in[5];
  float* out = (float*)d_out;
  float* ws  = (float*)d_ws;

  unsigned short* HhB = (unsigned short*)ws;
  float* AS = ws + 12800000;
  float* AD = ws + 13600000;
  int* ib     = (int*)(ws + 14400000);
  int* cnt    = ib;
  int* lpre   = ib + 100000;
  int* bsum   = ib + 200000;
  int* boff   = ib + 200512;
  int* rowptr = ib + 201024;
  int* cursor = ib + 301056;
  int* csr    = ib + 401056;
  unsigned short* Wp = (unsigned short*)(ib + 2101056);

  hipMemsetAsync(cnt, 0, (size_t)NN * sizeof(int), stream);

  k_convW  <<<128, 256, 0, stream>>>(W, Wp);
  k_gemm   <<<(NN + 63) / 64, 256, 0, stream>>>(X, Wp, att_src, att_dst, HhB, AS, AD);
  k_hist   <<<(ETOT + 255) / 256, 256, 0, stream>>>(ei, cnt);
  k_scan1  <<<NB, 256, 0, stream>>>(cnt, lpre, bsum);
  k_scan2  <<<1, 512, 0, stream>>>(bsum, boff);
  k_scan3  <<<NB, 256, 0, stream>>>(lpre, boff, rowptr, cursor);
  k_scatter<<<(ETOT + 255) / 256, 256, 0, stream>>>(ei, cursor, csr);
  k_gat    <<<NN / 4, 256, 0, stream>>>(rowptr, csr, AS, AD, HhB, bias, out);
}

// Round 7
// 416.650 us; speedup vs baseline: 1.2886x; 1.1630x over previous
//
#include <hip/hip_runtime.h>

// Problem constants (fixed by the reference setup)
#define NN 100000          // N_NODES
#define NE 1600000         // N_EDGES
#define IND 128            // IN_DIM
#define FD 32              // OUT_DIM
#define NH 8               // HEADS
#define HF 256             // NH*FD
#define ETOT 1700000       // NE + NN self loops
#define NB 391             // ceil(NN/256) scan blocks
#define GB 1563            // gemm blocks (ceil(NN/64))
#define HB 6641            // hist blocks (ceil(ETOT/256))

typedef __attribute__((ext_vector_type(8))) short bfrag;    // 8 bf16 (4 VGPRs)
typedef __attribute__((ext_vector_type(4))) float ffrag;    // 4 fp32 acc
typedef __attribute__((ext_vector_type(8))) unsigned short us8;

// bf16 helpers (RNE), bit-level to avoid header variance
static __device__ __forceinline__ unsigned short f2bf(float f) {
  union { float f; unsigned u; } v; v.f = f;
  unsigned r = v.u + 0x7FFF + ((v.u >> 16) & 1);
  return (unsigned short)(r >> 16);
}
static __device__ __forceinline__ float bf2f(unsigned short u) {
  union { unsigned u; float f; } v; v.u = ((unsigned)u) << 16;
  return v.f;
}

// ---------------------------------------------------------------------------
// K0: pack W (fp32 [128][256]) into MFMA B-operand order, bf16:
// Wp[(kt*256 + c)*32 + kk] = bf16(W[(kt*32+kk)*256 + c]).
// ---------------------------------------------------------------------------
__global__ __launch_bounds__(256) void k_convW(const float* __restrict__ W,
                                               unsigned short* __restrict__ Wp) {
  int tid = blockIdx.x * 256 + threadIdx.x;   // 32768 threads
  int kk = tid & 31, c = (tid >> 5) & 255, kt = tid >> 13;
  Wp[tid] = f2bf(W[(kt * 32 + kk) * HF + c]);
}

// ---------------------------------------------------------------------------
// K1: fused [MFMA projection GEMM + logits] | [dst histogram].
// Blocks < GB: 64 nodes x 256 cols, 4 waves. MFMA core as R6 (verified).
// New epilogue (R6 post-mortem: 16-sync per-head transpose cost ~70 us):
//   - ONE bf16 LDS transpose of the whole 64x256 C tile (row stride 272
//     ushorts = 544 B = bank+8 per row -> quad-groups land on disjoint
//     8-bank spans: conflict-free writes)
//   - coalesced HhB store: chunk mapping t+j*256 -> 1 KB/instr per wave
//   - logits from bf16 h (what k_gat consumes) with fp32 att/accumulate;
//     k8 rotated by row to cut LDS read conflicts 16-way -> 4-way
// Blocks >= GB: histogram of dst degree + per-edge rank re[e] (enables the
// atomic-free scatter). Atomic-bound work hides under the GEMM blocks.
// ---------------------------------------------------------------------------
__global__ __launch_bounds__(256) void k_gemm_hist(const float* __restrict__ X,
                                                   const unsigned short* __restrict__ Wp,
                                                   const float* __restrict__ att_src,
                                                   const float* __restrict__ att_dst,
                                                   const int* __restrict__ ei,
                                                   unsigned short* __restrict__ HhB,
                                                   float* __restrict__ AS,
                                                   float* __restrict__ AD,
                                                   int* __restrict__ cnt,
                                                   int* __restrict__ re) {
  __shared__ __align__(16) unsigned short buf[64 * 272];   // 34816 B
  const int t = threadIdx.x;

  if (blockIdx.x >= GB) {          // ---- histogram branch ----
    int e = (blockIdx.x - GB) * 256 + t;
    if (e < ETOT) {
      int d = (e < NE) ? ei[NE + e] : (e - NE);
      re[e] = atomicAdd(&cnt[d], 1);
    }
    return;
  }

  // ---- GEMM branch ----
  const int n0 = blockIdx.x * 64;

  // stage X tile fp32 -> bf16 LDS (stride 136 ushorts)
#pragma unroll
  for (int j = 0; j < 8; ++j) {
    int g = t + j * 256;            // float4-group id, 0..2047
    int r = g >> 5, c4 = g & 31;
    int gr = n0 + r; if (gr >= NN) gr = NN - 1;   // tail clamp (unused values)
    float4 x = *(const float4*)(X + (size_t)gr * IND + c4 * 4);
    ushort4 u;
    u.x = f2bf(x.x); u.y = f2bf(x.y); u.z = f2bf(x.z); u.w = f2bf(x.w);
    *(ushort4*)(buf + r * 136 + c4 * 4) = u;
  }
  __syncthreads();

  const int w = t >> 6, lane = t & 63;
  const int quad = lane >> 4, m = lane & 15;
  const int rb = w * 16;

  bfrag afr[4];
#pragma unroll
  for (int kt = 0; kt < 4; ++kt)
    afr[kt] = *(const bfrag*)(buf + (rb + m) * 136 + kt * 32 + quad * 8);
  __syncthreads();                  // all A-fragments in regs before buf reuse

  ffrag acc[16];
#pragma unroll
  for (int ct = 0; ct < 16; ++ct) {
    ffrag c = {0.f, 0.f, 0.f, 0.f};
#pragma unroll
    for (int kt = 0; kt < 4; ++kt) {
      bfrag b = *(const bfrag*)(Wp + ((kt * 256 + ct * 16 + m) << 5) + quad * 8);
      c = __builtin_amdgcn_mfma_f32_16x16x32_bf16(afr[kt], b, c, 0, 0, 0);
    }
    acc[ct] = c;
  }

  // one-shot bf16 transpose: C/D layout col=ct*16+m, row=quad*4+r
#pragma unroll
  for (int ct = 0; ct < 16; ++ct)
#pragma unroll
    for (int r = 0; r < 4; ++r)
      buf[(rb + quad * 4 + r) * 272 + ct * 16 + m] = f2bf(acc[ct][r]);
  __syncthreads();

  // coalesced HhB store: 64 consecutive lanes cover 1 KB contiguous
#pragma unroll
  for (int j = 0; j < 8; ++j) {
    int chunk = t + j * 256;        // 16B-chunk id, 0..2047
    int row = chunk >> 5, c16 = chunk & 31;
    int node = n0 + row;
    if (node < NN) {
      us8 v = *(const us8*)(buf + row * 272 + c16 * 8);
      *(us8*)(HhB + (size_t)node * HF + c16 * 8) = v;
    }
  }

  // logits: thread owns (row, 2 heads); k8 rotated by row (4-way max conflict)
  {
    int row = t >> 2, seg = t & 3;
    int node = n0 + row;
    if (node < NN) {
      const unsigned short* p = buf + row * 272 + seg * 64;
      float ss0 = 0.f, dd0 = 0.f, ss1 = 0.f, dd1 = 0.f;
#pragma unroll
      for (int k8 = 0; k8 < 4; ++k8) {
        int idx = (k8 + row) & 3;               // rotation: bank spread
        us8 a = *(const us8*)(p + idx * 8);
        us8 b = *(const us8*)(p + 32 + idx * 8);
        float4 sa0 = *(const float4*)(att_src + seg * 64 + idx * 8);
        float4 sa1 = *(const float4*)(att_src + seg * 64 + idx * 8 + 4);
        float4 sb0 = *(const float4*)(att_src + seg * 64 + 32 + idx * 8);
        float4 sb1 = *(const float4*)(att_src + seg * 64 + 32 + idx * 8 + 4);
        float4 da0 = *(const float4*)(att_dst + seg * 64 + idx * 8);
        float4 da1 = *(const float4*)(att_dst + seg * 64 + idx * 8 + 4);
        float4 db0 = *(const float4*)(att_dst + seg * 64 + 32 + idx * 8);
        float4 db1 = *(const float4*)(att_dst + seg * 64 + 32 + idx * 8 + 4);
        ss0 += bf2f(a[0])*sa0.x + bf2f(a[1])*sa0.y + bf2f(a[2])*sa0.z + bf2f(a[3])*sa0.w
             + bf2f(a[4])*sa1.x + bf2f(a[5])*sa1.y + bf2f(a[6])*sa1.z + bf2f(a[7])*sa1.w;
        dd0 += bf2f(a[0])*da0.x + bf2f(a[1])*da0.y + bf2f(a[2])*da0.z + bf2f(a[3])*da0.w
             + bf2f(a[4])*da1.x + bf2f(a[5])*da1.y + bf2f(a[6])*da1.z + bf2f(a[7])*da1.w;
        ss1 += bf2f(b[0])*sb0.x + bf2f(b[1])*sb0.y + bf2f(b[2])*sb0.z + bf2f(b[3])*sb0.w
             + bf2f(b[4])*sb1.x + bf2f(b[5])*sb1.y + bf2f(b[6])*sb1.z + bf2f(b[7])*sb1.w;
        dd1 += bf2f(b[0])*db0.x + bf2f(b[1])*db0.y + bf2f(b[2])*db0.z + bf2f(b[3])*db0.w
             + bf2f(b[4])*db1.x + bf2f(b[5])*db1.y + bf2f(b[6])*db1.z + bf2f(b[7])*db1.w;
      }
      AS[node * NH + seg * 2]     = ss0;
      AS[node * NH + seg * 2 + 1] = ss1;
      AD[node * NH + seg * 2]     = dd0;
      AD[node * NH + seg * 2 + 1] = dd1;
    }
  }
}

// ---------------------------------------------------------------------------
// CSR: 2-level exclusive scan (hist fused above) + atomic-free scatter
// ---------------------------------------------------------------------------
__global__ __launch_bounds__(256) void k_scan1(const int* __restrict__ cnt,
                                               int* __restrict__ lpre,
                                               int* __restrict__ bsum) {
  __shared__ int sd[256];
  int t = threadIdx.x, i = blockIdx.x * 256 + t;
  int v = (i < NN) ? cnt[i] : 0;
  sd[t] = v; __syncthreads();
  for (int off = 1; off < 256; off <<= 1) {
    int x = (t >= off) ? sd[t - off] : 0;
    __syncthreads();
    sd[t] += x;
    __syncthreads();
  }
  if (i < NN) lpre[i] = sd[t] - v;
  if (t == 255) bsum[blockIdx.x] = sd[255];
}

__global__ __launch_bounds__(512) void k_scan2(const int* __restrict__ bsum,
                                               int* __restrict__ boff) {
  __shared__ int sd[512];
  int t = threadIdx.x;
  int v = (t < NB) ? bsum[t] : 0;
  sd[t] = v; __syncthreads();
  for (int off = 1; off < 512; off <<= 1) {
    int x = (t >= off) ? sd[t - off] : 0;
    __syncthreads();
    sd[t] += x;
    __syncthreads();
  }
  if (t < NB) boff[t] = sd[t] - v;
}

__global__ __launch_bounds__(256) void k_scan3(const int* __restrict__ lpre,
                                               const int* __restrict__ boff,
                                               int* __restrict__ rowptr) {
  int i = blockIdx.x * 256 + threadIdx.x;
  if (i < NN) rowptr[i] = boff[blockIdx.x] + lpre[i];
  if (i == 0) rowptr[NN] = ETOT;
}

__global__ __launch_bounds__(256) void k_scatter(const int* __restrict__ ei,
                                                 const int* __restrict__ rowptr,
                                                 const int* __restrict__ re,
                                                 int* __restrict__ csr) {
  int e = blockIdx.x * 256 + threadIdx.x;
  if (e >= ETOT) return;
  int s, d;
  if (e < NE) { s = ei[e]; d = ei[NE + e]; } else { s = d = e - NE; }
  csr[rowptr[d] + re[e]] = s;      // rank precomputed in k_gemm_hist: no atomics
}

// ---------------------------------------------------------------------------
// K2: single-pass GAT aggregation (unchanged — at the delivered-BW wall:
// 870 MB logical gather / 138 us = 6.3 TB/s). One wave per dst node.
// ---------------------------------------------------------------------------
__global__ __launch_bounds__(256) void k_gat(const int* __restrict__ rowptr,
                                             const int* __restrict__ csr,
                                             const float* __restrict__ AS,
                                             const float* __restrict__ AD,
                                             const unsigned short* __restrict__ HhB,
                                             const float* __restrict__ bias,
                                             float* __restrict__ out) {
  const int d = blockIdx.x * 4 + (threadIdx.x >> 6);   // 25000*4 == NN exactly
  const int lane = threadIdx.x & 63;
  const int hh = lane >> 3, sub = lane & 7;
  const int start = rowptr[d], end = rowptr[d + 1];
  const float ad = AD[d * NH + hh];

  float den = 0.f, a0 = 0.f, a1 = 0.f, a2 = 0.f, a3 = 0.f;

  for (int base = start; base < end; base += 64) {
    int srcs = 0;
    if (base + lane < end) srcs = csr[base + lane];
    int m = end - base; if (m > 64) m = 64;
    int t = 0;
    for (; t + 1 < m; t += 2) {               // 2-way unroll for load ILP
      int s0 = __shfl(srcs, t, 64);
      int s1 = __shfl(srcs, t + 1, 64);
      float lg0 = AS[s0 * NH + hh] + ad;
      float lg1 = AS[s1 * NH + hh] + ad;
      ushort4 h0 = *(const ushort4*)(HhB + (size_t)s0 * HF + hh * 32 + sub * 4);
      ushort4 h1 = *(const ushort4*)(HhB + (size_t)s1 * HF + hh * 32 + sub * 4);
      lg0 = lg0 > 0.f ? lg0 : 0.2f * lg0;
      lg1 = lg1 > 0.f ? lg1 : 0.2f * lg1;
      float e0 = __expf(lg0), e1 = __expf(lg1);
      den += e0 + e1;
      a0 += e0 * bf2f(h0.x) + e1 * bf2f(h1.x);
      a1 += e0 * bf2f(h0.y) + e1 * bf2f(h1.y);
      a2 += e0 * bf2f(h0.z) + e1 * bf2f(h1.z);
      a3 += e0 * bf2f(h0.w) + e1 * bf2f(h1.w);
    }
    if (t < m) {
      int s0 = __shfl(srcs, t, 64);
      float lg0 = AS[s0 * NH + hh] + ad;
      ushort4 h0 = *(const ushort4*)(HhB + (size_t)s0 * HF + hh * 32 + sub * 4);
      lg0 = lg0 > 0.f ? lg0 : 0.2f * lg0;
      float e0 = __expf(lg0);
      den += e0;
      a0 += e0 * bf2f(h0.x); a1 += e0 * bf2f(h0.y);
      a2 += e0 * bf2f(h0.z); a3 += e0 * bf2f(h0.w);
    }
  }

  const float inv = 1.f / (den + 1e-16f);
  a0 *= inv; a1 *= inv; a2 *= inv; a3 *= inv;

#pragma unroll
  for (int off = 8; off < 64; off <<= 1) {    // sum over the 8 heads
    a0 += __shfl_xor(a0, off, 64);
    a1 += __shfl_xor(a1, off, 64);
    a2 += __shfl_xor(a2, off, 64);
    a3 += __shfl_xor(a3, off, 64);
  }

  if (lane < 8) {
    float4 o;
    o.x = a0 * 0.125f + bias[sub * 4 + 0];
    o.y = a1 * 0.125f + bias[sub * 4 + 1];
    o.z = a2 * 0.125f + bias[sub * 4 + 2];
    o.w = a3 * 0.125f + bias[sub * 4 + 3];
    *(float4*)(out + (size_t)d * FD + sub * 4) = o;
  }
}

// ---------------------------------------------------------------------------
// Workspace layout:
//   HhB    bf16[N*256]            floats [0,          12,800,000)   51.2 MB
//   AS     float[N*8]                    [12,800,000, 13,600,000)    3.2 MB
//   AD     float[N*8]                    [13,600,000, 14,400,000)    3.2 MB
//   ints (base = ws + 14,400,000):
//     cnt    [0,         100,000)
//     lpre   [100,000,   200,000)
//     bsum   [200,000,   200,512)
//     boff   [200,512,   201,024)
//     rowptr [201,024,   301,056)
//     re     [301,056,   2,001,056)   per-edge rank, 6.8 MB
//     csr    [2,001,056, 3,701,056)   8.4 MB
//     Wp     [3,701,056, 3,717,440)   32768 bf16
// ---------------------------------------------------------------------------
extern "C" void kernel_launch(void* const* d_in, const int* in_sizes, int n_in,
                              void* d_out, int out_size, void* d_ws, size_t ws_size,
                              hipStream_t stream) {
  const float* X       = (const float*)d_in[0];
  const int*   ei      = (const int*)d_in[1];
  const float* W       = (const float*)d_in[2];
  const float* att_src = (const float*)d_in[3];
  const float* att_dst = (const float*)d_in[4];
  const float* bias    = (const float*)d_in[5];
  float* out = (float*)d_out;
  float* ws  = (float*)d_ws;

  unsigned short* HhB = (unsigned short*)ws;
  float* AS = ws + 12800000;
  float* AD = ws + 13600000;
  int* ib     = (int*)(ws + 14400000);
  int* cnt    = ib;
  int* lpre   = ib + 100000;
  int* bsum   = ib + 200000;
  int* boff   = ib + 200512;
  int* rowptr = ib + 201024;
  int* re     = ib + 301056;
  int* csr    = ib + 2001056;
  unsigned short* Wp = (unsigned short*)(ib + 3701056);

  hipMemsetAsync(cnt, 0, (size_t)NN * sizeof(int), stream);

  k_convW    <<<128, 256, 0, stream>>>(W, Wp);
  k_gemm_hist<<<GB + HB, 256, 0, stream>>>(X, Wp, att_src, att_dst, ei,
                                           HhB, AS, AD, cnt, re);
  k_scan1    <<<NB, 256, 0, stream>>>(cnt, lpre, bsum);
  k_scan2    <<<1, 512, 0, stream>>>(bsum, boff);
  k_scan3    <<<NB, 256, 0, stream>>>(lpre, boff, rowptr);
  k_scatter  <<<HB, 256, 0, stream>>>(ei, rowptr, re, csr);
  k_gat      <<<NN / 4, 256, 0, stream>>>(rowptr, csr, AS, AD, HhB, bias, out);
}